// Round 2
// baseline (404.985 us; speedup 1.0000x reference)
//
#include <hip/hip_runtime.h>

// LSTM: B=2048, T=512, I=6, H=50, O=3. fp32 in/out, bf16 MFMA inner matmul.
//
// R2: NB=4 batch rows/WG, grid=512 -> 2 WGs/CU (2 waves/SIMD) so per-step
// stalls of one WG are hidden by the other. Activation lanes are PACKED:
// after MFMA, lanes col<4 ds_write_b128 their 4 gate regs into a wave-private
// LDS scratch in merged order; one ds_read_b128 gives every lane one (b,h)
// pair -> 10 transcendental instrs/wave/step instead of ~32. Same-wave LDS
// ops are in-order, so no extra barrier (still 1 barrier/step).
//
// Per step: G^T = W' @ [h|x|1]^T via mfma_f32_16x16x32_bf16, column
// permutation j' = 4*hidx + gate so one lane's 4 acc regs = (i,f,g,o) of one
// (batch,hidx) pair (C-layout col=lane&15 -> batch, row=quad*4+reg -> j').

#define L2E 1.44269504088896340736f

typedef float  f32x4  __attribute__((ext_vector_type(4)));
typedef short  s16x8  __attribute__((ext_vector_type(8)));   // 8 bf16 bit-patterns

__device__ __forceinline__ float fast_exp2(float x){ return __builtin_amdgcn_exp2f(x); }
__device__ __forceinline__ float fast_rcp (float x){ return __builtin_amdgcn_rcpf(x); }
__device__ __forceinline__ float sigm (float x){ return fast_rcp(1.0f + fast_exp2(-L2E * x)); }
__device__ __forceinline__ float tanhf_(float x){ return 1.0f - 2.0f * fast_rcp(1.0f + fast_exp2((2.0f*L2E) * x)); }

// float -> bf16 bits, round-to-nearest-even
__device__ __forceinline__ unsigned short f2bf(float f){
  unsigned u = __builtin_bit_cast(unsigned, f);
  u = (u + 0x7FFFu + ((u >> 16) & 1u)) >> 16;
  return (unsigned short)u;
}

constexpr int B_ = 2048, T_ = 512, I_ = 6, H_ = 50;
constexpr int NB = 4;     // batch rows per WG  (grid = 512 = 2 WGs/CU)
constexpr int AP = 72;    // A-row pitch in bf16 elems (144 B, 16B-aligned)
constexpr int NT = 13;    // j' tiles: 13*16 = 208 >= 200

__global__ __launch_bounds__(256, 2)
void lstm_kernel(const float* __restrict__ x,
                 const float* __restrict__ W_ih, const float* __restrict__ W_hh,
                 const float* __restrict__ b_ih, const float* __restrict__ b_hh,
                 const float* __restrict__ W_out, const float* __restrict__ b_out,
                 float* __restrict__ out)
{
  __shared__ unsigned short Abuf[2][16 * AP];  // [h(50)|x(6)|1|0pad] per batch row
  __shared__ float Gs[4][64][4];               // wave-private merged-gate scratch
  __shared__ float Hlast[NB][H_];

  const int tid  = threadIdx.x;
  const int lane = tid & 63;
  const int wave = tid >> 6;
  const int col  = lane & 15;   // MFMA N index = batch row
  const int quad = lane >> 4;   // MFMA row-group
  const int b0   = blockIdx.x * NB;

  // merged-lane identity: this lane's (batch, hidx) pair for activations
  const int mb   = lane & 3;            // merged batch row
  const int tsel = (lane >> 2) & 3;     // which of this wave's tiles
  const int mh   = 4 * (wave + 4 * tsel) + quad;  // merged hidden index

  // ---- init LDS to zero ----
  unsigned short* ab = &Abuf[0][0];
  for (int i = tid; i < 2 * 16 * AP; i += 256) ab[i] = 0;
  float* gz = &Gs[0][0][0];
  for (int i = tid; i < 4 * 64 * 4; i += 256) gz[i] = 0.0f;
  __syncthreads();
  if (tid < NB) {
    Abuf[0][tid*AP + 56] = 0x3F80;  // 1.0 bf16 (bias column), persistent
    Abuf[1][tid*AP + 56] = 0x3F80;
    const float* xp = x + (size_t)(b0 + tid) * T_ * I_;  // x(t=0)
    #pragma unroll
    for (int i = 0; i < 6; i++) Abuf[0][tid*AP + 50 + i] = f2bf(xp[i]);
  }

  // ---- load weight fragments (A-operand, once) ----
  // lane holds W' row j' = jt*16 + col, k-slice quad*8..+7 (+32 for kh=1)
  // W'[j'][k]: j' = 4*hidx+gate -> source row = gate*50 + hidx
  s16x8 wfrag[4][2];
  #pragma unroll
  for (int ti = 0; ti < 4; ti++) {
    const int jt = wave + 4 * ti;           // wave-uniform
    if (jt < NT) {
      const int jp = jt * 16 + col;
      #pragma unroll
      for (int kh = 0; kh < 2; kh++) {
        s16x8 w;
        #pragma unroll
        for (int kk = 0; kk < 8; kk++) {
          const int k = kh * 32 + quad * 8 + kk;
          float v = 0.0f;
          if (jp < 200) {
            const int hh = jp >> 2, g = jp & 3;
            const int row = g * 50 + hh;
            if      (k < 50) v = W_hh[row * 50 + k];
            else if (k < 56) v = W_ih[row * 6 + (k - 50)];
            else if (k == 56) v = b_ih[row] + b_hh[row];
          }
          w[kk] = (short)f2bf(v);
        }
        wfrag[ti][kh] = w;
      }
    }
  }

  // ---- x prefetch ring: 4 steps deep (wave 3, lanes 0..NB-1) ----
  const bool xduty = (wave == 3) && (lane < NB);
  float2 xr[4][3];
  if (xduty) {
    const float* xbase = x + (size_t)(b0 + lane) * T_ * I_;
    #pragma unroll
    for (int s = 1; s <= 4; s++) {      // x(s) -> slot s&3
      const float2* p = (const float2*)(xbase + (size_t)s * I_);
      xr[s & 3][0] = p[0]; xr[s & 3][1] = p[1]; xr[s & 3][2] = p[2];
    }
  }

  float c_   = 0.0f;
  float hreg = 0.0f;

  __syncthreads();

  #pragma unroll 2
  for (int t = 0; t < T_; t++) {
    const unsigned short* Ar = &Abuf[t & 1][0];
    unsigned short*       Aw = &Abuf[(t + 1) & 1][0];

    // write x(t+1) into next buffer, then refill ring slot with x(t+5)
    if (xduty) {
      if (t + 1 < T_) {
        const float2* s = xr[(t + 1) & 3];
        unsigned short* dst = Aw + lane * AP + 50;
        dst[0] = f2bf(s[0].x); dst[1] = f2bf(s[0].y);
        dst[2] = f2bf(s[1].x); dst[3] = f2bf(s[1].y);
        dst[4] = f2bf(s[2].x); dst[5] = f2bf(s[2].y);
      }
      if (t + 5 < T_) {
        const float2* p = (const float2*)(x + ((size_t)(b0 + lane) * T_ + (t + 5)) * I_);
        xr[(t + 1) & 3][0] = p[0]; xr[(t + 1) & 3][1] = p[1]; xr[(t + 1) & 3][2] = p[2];
      }
    }

    // B-operand fragments: B[k][n=batch] read from [b][k]-major LDS
    const unsigned short* arow = Ar + col * AP;
    s16x8 bfr0 = *(const s16x8*)(arow + quad * 8);        // k = quad*8..+7
    s16x8 bfr1 = *(const s16x8*)(arow + 32 + quad * 8);   // k = 32+quad*8..+7

    // MFMA per tile; lanes col<NB scatter their 4 gate regs into merged slots
    #pragma unroll
    for (int ti = 0; ti < 4; ti++) {
      const int jt = wave + 4 * ti;
      if (jt < NT) {
        f32x4 a = {0.f, 0.f, 0.f, 0.f};
        a = __builtin_amdgcn_mfma_f32_16x16x32_bf16(wfrag[ti][0], bfr0, a, 0, 0, 0);
        a = __builtin_amdgcn_mfma_f32_16x16x32_bf16(wfrag[ti][1], bfr1, a, 0, 0, 0);
        if (col < NB) *(f32x4*)&Gs[wave][col + 4 * ti + 16 * quad][0] = a;
      }
    }

    // merged read: every lane gets the (i,f,g,o) of its (mb, mh) pair.
    // Same-wave LDS ops are in-order: no barrier needed.
    const f32x4 g = *(const f32x4*)&Gs[wave][lane][0];
    const float gi = sigm (g[0]);
    const float gf = sigm (g[1]);
    const float gg = tanhf_(g[2]);
    const float go = sigm (g[3]);
    c_ = gf * c_ + gi * gg;
    const float hn = go * tanhf_(c_);
    hreg = hn;
    if (mh < H_) Aw[mb * AP + mh] = f2bf(hn);

    __syncthreads();  // writes to Aw visible; reads of Ar complete
  }

  // ---- epilogue: logits + softmax ----
  if (mh < H_) Hlast[mb][mh] = hreg;  // fp32 h_last
  __syncthreads();

  if (tid < NB) {
    float l[3];
    #pragma unroll
    for (int o = 0; o < 3; o++) {
      float s = b_out[o];
      for (int k = 0; k < H_; k++) s += W_out[o * H_ + k] * Hlast[tid][k];
      l[o] = s;
    }
    const float m  = fmaxf(l[0], fmaxf(l[1], l[2]));
    const float e0 = fast_exp2((l[0] - m) * L2E);
    const float e1 = fast_exp2((l[1] - m) * L2E);
    const float e2 = fast_exp2((l[2] - m) * L2E);
    const float inv = fast_rcp(e0 + e1 + e2);
    float* op = out + (size_t)(b0 + tid) * 3;
    op[0] = e0 * inv; op[1] = e1 * inv; op[2] = e2 * inv;
  }
}

extern "C" void kernel_launch(void* const* d_in, const int* in_sizes, int n_in,
                              void* d_out, int out_size, void* d_ws, size_t ws_size,
                              hipStream_t stream) {
  const float* x     = (const float*)d_in[0];
  const float* W_ih  = (const float*)d_in[1];
  const float* W_hh  = (const float*)d_in[2];
  const float* b_ih  = (const float*)d_in[3];
  const float* b_hh  = (const float*)d_in[4];
  const float* W_out = (const float*)d_in[5];
  const float* b_out = (const float*)d_in[6];
  lstm_kernel<<<B_ / NB, 256, 0, stream>>>(x, W_ih, W_hh, b_ih, b_hh,
                                           W_out, b_out, (float*)d_out);
}

// Round 3
// 321.411 us; speedup vs baseline: 1.2600x; 1.2600x over previous
//
#include <hip/hip_runtime.h>

// LSTM: B=2048, T=512, I=6, H=50, O=3. fp32 in/out, bf16 MFMA inner matmul.
//
// R3: NO global loads inside the step loop. R1/R2 were killed by the
// compiler's `s_waitcnt vmcnt(0)` before every s_barrier: the per-step x
// prefetch load (~900 cyc HBM latency) was drained at every barrier, ~800
// idle cyc/step for the whole WG. Fix: stage all of this WG's x (4 rows x
// 12 KB fp32 = 48 KB) into LDS up front with one contiguous float4 copy;
// the per-step x feed becomes LDS->reg->LDS (lgkm-only, fast drain).
// Also: swizzled Gs index (ti^quad) turns the 4-way gate-scatter bank
// conflict into a free 2-way; x-copy duty on wave 3 (3 tiles vs wave 0's 4).
//
// Per step: G^T = W'[200x56] @ [h|x|1]^T via mfma_f32_16x16x32_bf16, column
// permutation j' = 4*hidx + gate so one lane's 4 acc regs = (i,f,g,o) of one
// (batch,hidx) pair (C-layout col=lane&15 -> batch, row=quad*4+reg -> j').
// NB=4 rows/WG, grid=512 -> 2 WGs/CU; 1 barrier/step; c-state in registers.

#define L2E 1.44269504088896340736f

typedef float  f32x4  __attribute__((ext_vector_type(4)));
typedef float  f32x4v __attribute__((ext_vector_type(4)));
typedef short  s16x8  __attribute__((ext_vector_type(8)));   // 8 bf16 bit-patterns

__device__ __forceinline__ float fast_exp2(float x){ return __builtin_amdgcn_exp2f(x); }
__device__ __forceinline__ float fast_rcp (float x){ return __builtin_amdgcn_rcpf(x); }
__device__ __forceinline__ float sigm (float x){ return fast_rcp(1.0f + fast_exp2(-L2E * x)); }
__device__ __forceinline__ float tanhf_(float x){ return 1.0f - 2.0f * fast_rcp(1.0f + fast_exp2((2.0f*L2E) * x)); }

// float -> bf16 bits, round-to-nearest-even
__device__ __forceinline__ unsigned short f2bf(float f){
  unsigned u = __builtin_bit_cast(unsigned, f);
  u = (u + 0x7FFFu + ((u >> 16) & 1u)) >> 16;
  return (unsigned short)u;
}

constexpr int B_ = 2048, T_ = 512, I_ = 6, H_ = 50;
constexpr int NB = 4;       // batch rows per WG  (grid = 512 = 2 WGs/CU)
constexpr int AP = 72;      // A-row pitch in bf16 elems (144 B)
constexpr int NT = 13;      // j' tiles: 13*16 = 208 >= 200
constexpr int T6 = T_ * I_; // floats per batch row of x

__global__ __launch_bounds__(256, 2)
void lstm_kernel(const float* __restrict__ x,
                 const float* __restrict__ W_ih, const float* __restrict__ W_hh,
                 const float* __restrict__ b_ih, const float* __restrict__ b_hh,
                 const float* __restrict__ W_out, const float* __restrict__ b_out,
                 float* __restrict__ out)
{
  __shared__ float Xs[NB][T6];                 // 48 KB: this WG's x, staged once
  __shared__ unsigned short Abuf[2][16 * AP];  // [h(50)|x(6)|1|0pad] per batch row
  __shared__ float Gs[4][64][4];               // wave-private merged-gate scratch
  __shared__ float Hlast[NB][H_];

  const int tid  = threadIdx.x;
  const int lane = tid & 63;
  const int wave = tid >> 6;
  const int col  = lane & 15;   // MFMA N index = batch row
  const int quad = lane >> 4;   // MFMA row-group
  const int b0   = blockIdx.x * NB;

  // merged-lane identity (matches swizzled Gs layout below):
  // slot L holds pair (col=L&3, ti=((L>>2)&3)^quad, quad=L>>4)
  const int mb = lane & 3;
  const int mh = 4 * (wave + 4 * (((lane >> 2) & 3) ^ quad)) + quad;

  // ---- stage x: contiguous fp32 copy (4 rows are contiguous in x) ----
  {
    const float4* src = (const float4*)(x + (size_t)b0 * T6);
    float4* dst = (float4*)&Xs[0][0];
    #pragma unroll
    for (int i = 0; i < (NB * T6 / 4) / 256; i++)
      dst[tid + 256 * i] = src[tid + 256 * i];
  }

  // ---- init LDS ----
  unsigned short* ab = &Abuf[0][0];
  for (int i = tid; i < 2 * 16 * AP; i += 256) ab[i] = 0;
  float* gz = &Gs[0][0][0];
  for (int i = tid; i < 4 * 64 * 4; i += 256) gz[i] = 0.0f;
  __syncthreads();
  if (tid < NB) {
    Abuf[0][tid*AP + 56] = 0x3F80;  // 1.0 bf16 (bias column), persistent
    Abuf[1][tid*AP + 56] = 0x3F80;
    #pragma unroll
    for (int i = 0; i < 6; i++) Abuf[0][tid*AP + 50 + i] = f2bf(Xs[tid][i]);  // x(0)
  }

  // ---- load weight fragments (A-operand, once) ----
  // lane holds W' row j' = jt*16 + col, k-slice quad*8..+7 (+32 for kh=1)
  // W'[j'][k]: j' = 4*hidx+gate -> source row = gate*50 + hidx
  s16x8 wfrag[4][2];
  #pragma unroll
  for (int ti = 0; ti < 4; ti++) {
    const int jt = wave + 4 * ti;           // wave-uniform
    if (jt < NT) {
      const int jp = jt * 16 + col;
      #pragma unroll
      for (int kh = 0; kh < 2; kh++) {
        s16x8 w;
        #pragma unroll
        for (int kk = 0; kk < 8; kk++) {
          const int k = kh * 32 + quad * 8 + kk;
          float v = 0.0f;
          if (jp < 200) {
            const int hh = jp >> 2, g = jp & 3;
            const int row = g * 50 + hh;
            if      (k < 50) v = W_hh[row * 50 + k];
            else if (k < 56) v = W_ih[row * 6 + (k - 50)];
            else if (k == 56) v = b_ih[row] + b_hh[row];
          }
          w[kk] = (short)f2bf(v);
        }
        wfrag[ti][kh] = w;
      }
    }
  }

  float c_   = 0.0f;
  float hreg = 0.0f;

  __syncthreads();

  #pragma unroll 2
  for (int t = 0; t < T_; t++) {
    const unsigned short* Ar = &Abuf[t & 1][0];
    unsigned short*       Aw = &Abuf[(t + 1) & 1][0];

    // x(t+1) feed: LDS->reg->LDS only (no vmcnt at the barrier). Wave 3 has
    // one fewer j'-tile than wave 0, so it takes the copy duty.
    if (wave == 3 && lane < NB && t + 1 < T_) {
      const float* xs = &Xs[lane][(t + 1) * I_];
      const float2 a0 = *(const float2*)(xs);
      const float2 a1 = *(const float2*)(xs + 2);
      const float2 a2 = *(const float2*)(xs + 4);
      unsigned* dst = (unsigned*)(Aw + lane * AP + 50);
      dst[0] = (unsigned)f2bf(a0.x) | ((unsigned)f2bf(a0.y) << 16);
      dst[1] = (unsigned)f2bf(a1.x) | ((unsigned)f2bf(a1.y) << 16);
      dst[2] = (unsigned)f2bf(a2.x) | ((unsigned)f2bf(a2.y) << 16);
    }

    // B-operand fragments: B[k][n=batch] read from [b][k]-major LDS
    const unsigned short* arow = Ar + col * AP;
    s16x8 bfr0 = *(const s16x8*)(arow + quad * 8);        // k = quad*8..+7
    s16x8 bfr1 = *(const s16x8*)(arow + 32 + quad * 8);   // k = 32+quad*8..+7

    // MFMA per tile; lanes col<NB scatter gates into swizzled merged slots
    // (idx = col + 4*(ti^quad) + 16*quad -> 2-way bank aliasing, free)
    #pragma unroll
    for (int ti = 0; ti < 4; ti++) {
      const int jt = wave + 4 * ti;
      if (jt < NT) {
        f32x4 a = {0.f, 0.f, 0.f, 0.f};
        a = __builtin_amdgcn_mfma_f32_16x16x32_bf16(wfrag[ti][0], bfr0, a, 0, 0, 0);
        a = __builtin_amdgcn_mfma_f32_16x16x32_bf16(wfrag[ti][1], bfr1, a, 0, 0, 0);
        if (col < NB) *(f32x4*)&Gs[wave][col + 4 * (ti ^ quad) + 16 * quad][0] = a;
      }
    }

    // merged read: every lane gets (i,f,g,o) of its (mb, mh) pair.
    // Same-wave LDS ops are in-order: no extra barrier.
    const f32x4 g = *(const f32x4*)&Gs[wave][lane][0];
    const float gi = sigm (g[0]);
    const float gf = sigm (g[1]);
    const float gg = tanhf_(g[2]);
    const float go = sigm (g[3]);
    c_ = gf * c_ + gi * gg;
    const float hn = go * tanhf_(c_);
    hreg = hn;
    if (mh < H_) Aw[mb * AP + mh] = f2bf(hn);

    __syncthreads();  // writes to Aw visible; reads of Ar complete (lgkm only)
  }

  // ---- epilogue: logits + softmax ----
  if (mh < H_) Hlast[mb][mh] = hreg;  // fp32 h_last
  __syncthreads();

  if (tid < NB) {
    float l[3];
    #pragma unroll
    for (int o = 0; o < 3; o++) {
      float s = b_out[o];
      for (int k = 0; k < H_; k++) s += W_out[o * H_ + k] * Hlast[tid][k];
      l[o] = s;
    }
    const float m  = fmaxf(l[0], fmaxf(l[1], l[2]));
    const float e0 = fast_exp2((l[0] - m) * L2E);
    const float e1 = fast_exp2((l[1] - m) * L2E);
    const float e2 = fast_exp2((l[2] - m) * L2E);
    const float inv = fast_rcp(e0 + e1 + e2);
    float* op = out + (size_t)(b0 + tid) * 3;
    op[0] = e0 * inv; op[1] = e1 * inv; op[2] = e2 * inv;
  }
}

extern "C" void kernel_launch(void* const* d_in, const int* in_sizes, int n_in,
                              void* d_out, int out_size, void* d_ws, size_t ws_size,
                              hipStream_t stream) {
  const float* x     = (const float*)d_in[0];
  const float* W_ih  = (const float*)d_in[1];
  const float* W_hh  = (const float*)d_in[2];
  const float* b_ih  = (const float*)d_in[3];
  const float* b_hh  = (const float*)d_in[4];
  const float* W_out = (const float*)d_in[5];
  const float* b_out = (const float*)d_in[6];
  lstm_kernel<<<B_ / NB, 256, 0, stream>>>(x, W_ih, W_hh, b_ih, b_hh,
                                           W_out, b_out, (float*)d_out);
}